// Round 11
// baseline (913.536 us; speedup 1.0000x reference)
//
#include <hip/hip_runtime.h>
#include <hip/hip_bf16.h>
#include <stdint.h>
#include <stddef.h>

typedef __hip_bfloat16 bf16;
typedef __attribute__((ext_vector_type(8))) __bf16 bf16x8;
typedef __attribute__((ext_vector_type(4))) float f32x4;

__device__ __forceinline__ bf16 f2b(float x) { return __float2bfloat16(x); }

// async global->LDS copy, 16B per lane. LDS dest must be wave-uniform base + lane*16.
__device__ __forceinline__ void async_copy16(const bf16* g, bf16* l) {
    __builtin_amdgcn_global_load_lds(
        (const __attribute__((address_space(1))) unsigned int*)g,
        (__attribute__((address_space(3))) unsigned int*)l,
        16, 0, 0);
}

// XCD-aware remap: blocks dispatch round-robin to 8 XCDs by l%8. Map each group of
// 64 consecutive l to 8 m-tiles x 8 n-tiles so the 8 blocks of one XCD share ONE
// m-tile -> A row-tile fetched once into that XCD's L2. (r8: FETCH 1.05GB -> 128MB)
__device__ __forceinline__ void remap_xcd(int l, int mt, int& mtile, int& ntile) {
    int g  = l >> 6;
    int r  = l & 63;
    int gm = g << 3;
    if (gm + 8 <= mt) { mtile = gm + (r & 7); ntile = r >> 3; }
    else { int p = mt - gm; mtile = gm + (r % p); ntile = r / p; }  // tail group
}

// ---------------------------------------------------------------- utility kernels
__global__ void zero_kernel(float* __restrict__ p, int n) {
    int i = blockIdx.x * blockDim.x + threadIdx.x;
    if (i < n) p[i] = 0.f;
}

// W1T[n*320 + p]: padded-triplet layout. p = t*32 + q; q<30 -> W1[(t*30+q)*1024 + n], else 0.
__global__ void transpose_w1_pad32(const float* __restrict__ W1, bf16* __restrict__ WT) {
    int idx = blockIdx.x * blockDim.x + threadIdx.x;
    if (idx >= 1024 * 320) return;
    int n = idx / 320;
    int p = idx - n * 320;
    int t = p >> 5;
    int q = p & 31;
    float v = (q < 30) ? W1[(size_t)(t * 30 + q) * 1024 + n] : 0.f;
    WT[idx] = f2b(v);
}

// Tiled transpose+cast for W2: WT[n*Kpad+k] = bf16(W[k*N+n]). 64x64 tiles via LDS.
__global__ __launch_bounds__(256)
void transpose_pad_tiled(const float* __restrict__ W, bf16* __restrict__ WT,
                         int K, int N, int Kpad) {
    __shared__ bf16 tile[64][65];
    const int t = threadIdx.x;
    const int tk = blockIdx.x * 64;
    const int tn = blockIdx.y * 64;
    #pragma unroll
    for (int r = 0; r < 16; ++r) {
        int kl = (t >> 6) + r * 4;
        int nl = t & 63;
        int k = tk + kl, n = tn + nl;
        float v = (k < K) ? W[(size_t)k * N + n] : 0.f;
        tile[kl][nl] = f2b(v);
    }
    __syncthreads();
    #pragma unroll
    for (int r = 0; r < 16; ++r) {
        int nl = (t >> 6) + r * 4;
        int kl = t & 63;
        WT[(size_t)(tn + nl) * Kpad + tk + kl] = tile[kl][nl];
    }
}

// ---------------------------------------------------------------- feature kernel (r8 winner)
// 128 rows/block; features computed once, staged in LDS (XOR-swizzled chunks),
// stored fully coalesced bf16x8. feat layout (linear): row*320 + t*32 + q.
__global__ __launch_bounds__(256)
void feat_kernel(const float* __restrict__ S, const float* __restrict__ E,
                 bf16* __restrict__ feat) {
    __shared__ bf16 sF[128 * 320];
    const int tid = threadIdx.x;
    const size_t r0 = (size_t)blockIdx.x * 128;
    const int row = tid >> 1, tp = tid & 1;

    #pragma unroll
    for (int c = 0; c < 5; ++c) {
        int t = c * 2 + tp;
        const float* sp = S + (r0 + row) * 30 + t * 3;
        float fi = sp[0], fj = sp[1], d = sp[2];
        int ii = (int)fi;
        int jj = (int)fj;
        bf16 f[32];
        #pragma unroll
        for (int q = 0; q < 10; ++q) f[q]      = f2b((ii != 0) ? E[ii * 10 + q] : 0.f);
        #pragma unroll
        for (int q = 0; q < 10; ++q) f[10 + q] = f2b((jj != 0) ? E[jj * 10 + q] : 0.f);
        #pragma unroll
        for (int q = 0; q < 10; ++q) {
            float df = (float)(q + 1) * 0.7f - d;
            f[20 + q] = f2b((ii != 0) ? __expf(-df * df) : 0.f);   // GAMMA = 1
        }
        f[30] = f2b(0.f);
        f[31] = f2b(0.f);
        #pragma unroll
        for (int j = 0; j < 4; ++j) {
            int c0 = t * 4 + j;
            *(bf16x8*)&sF[row * 320 + ((c0 ^ (row & 7)) << 3)] = *(const bf16x8*)&f[j * 8];
        }
    }
    __syncthreads();
    #pragma unroll
    for (int i = 0; i < 20; ++i) {
        int c2 = i * 256 + tid;        // 0..5119
        int r  = c2 / 40;
        int c  = c2 - r * 40;
        int p  = c ^ (r & 7);
        *(bf16x8*)(feat + r0 * 320 + (size_t)c2 * 8) = *(const bf16x8*)&sF[r * 320 + p * 8];
    }
}

// ---------------------------------------------------------------- MFMA GEMM
// C[M,N] = A[M,K] @ BT[N,K]^T ; 128x128 tile, BK=64, 4 waves (2x2), 4x4 16x16x32 frags.
// r11: A-fragments loaded DIRECTLY from global into VGPRs (A is linear; 16 rows x
// 64B-contiguous per frag, L2-hot via XCD remap). Only B goes through LDS
// (global_load_lds, XOR-swizzled) -> the per-iter barrier drain covers 16KB not
// 32KB, and the unrolled loop lets the compiler hoist/pipeline the A register
// loads. KTOTAL and LDA compile-time -> all addresses immediate-folded.
// EPI==0: C = relu(acc + bias) stored bf16.   EPI==1: outf[row] += relu-dot-w3.
template <int EPI, int KTOTAL, int LDA>
__global__ __launch_bounds__(256)
void gemm_kernel(const bf16* __restrict__ A, const bf16* __restrict__ BT,
                 const float* __restrict__ bias, bf16* __restrict__ C,
                 float* __restrict__ outf, const float* __restrict__ w3,
                 int ldbt, int ldc, int mt) {
    __shared__ bf16 sB[128 * 64];
    const int tid  = threadIdx.x;
    const int lane = tid & 63;
    const int wave = tid >> 6;
    const int wr = wave >> 1, wc = wave & 1;
    const int l16 = lane & 15, quad = lane >> 4;
    int mtile, ntile;
    remap_xcd(blockIdx.x, mt, mtile, ntile);
    const size_t m0 = (size_t)mtile * 128;
    const int    n0 = ntile * 128;

    // per-lane A base: row (m0 + wr*64 + l16), k-offset quad*8. mi/kk/s2 offsets
    // are compile-time multiples -> fold to immediates / loop-invariant adds.
    const bf16* aBase = A + (m0 + wr * 64 + l16) * LDA + quad * 8;

    // loop-invariant B staging bases
    const bf16* gB[4];
    #pragma unroll
    for (int i = 0; i < 4; ++i) {
        int s   = i * 256 + tid;
        int row = s >> 3;
        int kof = (((s & 7) ^ (row & 7)) << 3);
        gB[i] = BT + (size_t)(n0 + row) * ldbt + kof;
    }

    f32x4 acc[4][4];
    #pragma unroll
    for (int i = 0; i < 4; ++i)
        #pragma unroll
        for (int j = 0; j < 4; ++j) acc[i][j] = (f32x4){0.f, 0.f, 0.f, 0.f};

    #pragma unroll
    for (int kk = 0; kk < KTOTAL; kk += 64) {
        #pragma unroll
        for (int i = 0; i < 4; ++i) {
            int s = i * 256 + tid;
            async_copy16(gB[i] + kk, &sB[s * 8]);
        }
        __syncthreads();
        #pragma unroll
        for (int s2 = 0; s2 < 2; ++s2) {
            int clog = s2 * 4 + quad;
            bf16x8 a[4], b[4];
            #pragma unroll
            for (int mi = 0; mi < 4; ++mi)
                a[mi] = *(const bf16x8*)(aBase + (size_t)mi * 16 * LDA + kk + s2 * 32);
            #pragma unroll
            for (int ni = 0; ni < 4; ++ni) {
                int r = wc * 64 + ni * 16 + l16;
                b[ni] = *(const bf16x8*)&sB[r * 64 + ((clog ^ (r & 7)) << 3)];
            }
            #pragma unroll
            for (int mi = 0; mi < 4; ++mi)
                #pragma unroll
                for (int ni = 0; ni < 4; ++ni)
                    acc[mi][ni] = __builtin_amdgcn_mfma_f32_16x16x32_bf16(
                        a[mi], b[ni], acc[mi][ni], 0, 0, 0);
        }
        __syncthreads();
    }

    if (EPI == 0) {
        #pragma unroll
        for (int mi = 0; mi < 4; ++mi) {
            #pragma unroll
            for (int ni = 0; ni < 4; ++ni) {
                int col = n0 + wc * 64 + ni * 16 + l16;
                float bv = bias[col];
                #pragma unroll
                for (int r = 0; r < 4; ++r) {
                    size_t row = m0 + wr * 64 + mi * 16 + quad * 4 + r;
                    float v = acc[mi][ni][r] + bv;
                    v = v > 0.f ? v : 0.f;
                    C[row * ldc + col] = f2b(v);
                }
            }
        }
    } else {
        #pragma unroll
        for (int mi = 0; mi < 4; ++mi) {
            #pragma unroll
            for (int r = 0; r < 4; ++r) {
                float p = 0.f;
                #pragma unroll
                for (int ni = 0; ni < 4; ++ni) {
                    int col = n0 + wc * 64 + ni * 16 + l16;
                    float v = acc[mi][ni][r] + bias[col];
                    v = v > 0.f ? v : 0.f;
                    p += v * w3[col];
                }
                #pragma unroll
                for (int off = 1; off < 16; off <<= 1)
                    p += __shfl_xor(p, off, 64);
                if (l16 == 0) {
                    size_t row = m0 + wr * 64 + mi * 16 + quad * 4 + r;
                    atomicAdd(&outf[row], p);
                }
            }
        }
    }
}

__global__ void final_kernel(const float* __restrict__ outf, const float* __restrict__ b3,
                             float* __restrict__ out, int n) {
    int i = blockIdx.x * blockDim.x + threadIdx.x;
    if (i < n) out[i] = outf[i] + b3[0];
}

// ---------------------------------------------------------------- zero-workspace fallback
#define FB_ROWS 8
__global__ __launch_bounds__(256)
void fallback_kernel(const float* __restrict__ S, const float* __restrict__ E,
                     const float* __restrict__ W1, const float* __restrict__ b1,
                     const float* __restrict__ W2, const float* __restrict__ b2,
                     const float* __restrict__ W3, const float* __restrict__ b3,
                     float* __restrict__ out) {
    __shared__ float feat[FB_ROWS][304];
    __shared__ float X1[FB_ROWS][1024];
    __shared__ float red[256];
    const int tid = threadIdx.x;
    const size_t r0 = (size_t)blockIdx.x * FB_ROWS;

    if (tid < FB_ROWS * 10) {
        int r = tid / 10, t = tid - r * 10;
        const float* s = S + (r0 + r) * 30 + t * 3;
        float fi = s[0], fj = s[1], d = s[2];
        int ii = (int)fi;
        int jj = (int)fj;
        float* o = &feat[r][t * 30];
        #pragma unroll
        for (int c = 0; c < 10; ++c) o[c]      = (ii != 0) ? E[ii * 10 + c] : 0.f;
        #pragma unroll
        for (int c = 0; c < 10; ++c) o[10 + c] = (jj != 0) ? E[jj * 10 + c] : 0.f;
        #pragma unroll
        for (int c = 0; c < 10; ++c) {
            float df = (float)(c + 1) * 0.7f - d;
            o[20 + c] = (ii != 0) ? __expf(-df * df) : 0.f;
        }
    }
    __syncthreads();

    for (int i = 0; i < FB_ROWS * 1024 / 256; ++i) {
        int idx = i * 256 + tid;
        int r = idx & (FB_ROWS - 1);
        int c = idx >> 3;
        float a = b1[c];
        for (int k = 0; k < 300; ++k)
            a += feat[r][k] * W1[(size_t)k * 1024 + c];
        X1[r][c] = a > 0.f ? a : 0.f;
    }
    __syncthreads();

    {
        int r  = tid & (FB_ROWS - 1);
        int cg = tid >> 3;
        float acc = 0.f;
        for (int cc = 0; cc < 32; ++cc) {
            int c = cg * 32 + cc;
            float a = b2[c];
            for (int k = 0; k < 1024; ++k)
                a += X1[r][k] * W2[(size_t)k * 1024 + c];
            a = a > 0.f ? a : 0.f;
            acc += a * W3[c];
        }
        red[tid] = acc;
    }
    __syncthreads();
    if (tid < FB_ROWS) {
        float s = 0.f;
        for (int g = 0; g < 32; ++g) s += red[g * FB_ROWS + tid];
        out[r0 + tid] = s + b3[0];
    }
}

// ---------------------------------------------------------------- launch
extern "C" void kernel_launch(void* const* d_in, const int* in_sizes, int n_in,
                              void* d_out, int out_size, void* d_ws, size_t ws_size,
                              hipStream_t stream) {
    const float* S  = (const float*)d_in[0];
    const float* E  = (const float*)d_in[1];
    const float* W1 = (const float*)d_in[2];
    const float* b1 = (const float*)d_in[3];
    const float* W2 = (const float*)d_in[4];
    const float* b2 = (const float*)d_in[5];
    const float* W3 = (const float*)d_in[6];
    const float* b3 = (const float*)d_in[7];
    float* out = (float*)d_out;

    const int Bn  = out_size;   // 131072
    const int HID = 1024;
    const int K1  = 320;

    const size_t MIN_WS = 16u * 1024u * 1024u;
    if (ws_size < MIN_WS) {
        fallback_kernel<<<Bn / FB_ROWS, 256, 0, stream>>>(S, E, W1, b1, W2, b2, W3, b3, out);
        return;
    }

    char* ws = (char*)d_ws;
    size_t off = 0;
    auto take = [&](size_t bytes) { char* p = ws + off; off += (bytes + 255) & ~(size_t)255; return p; };
    float* outf = (float*)take((size_t)Bn * sizeof(float));
    bf16*  W1T  = (bf16*) take((size_t)HID * K1 * sizeof(bf16));
    bf16*  W2T  = (bf16*) take((size_t)HID * HID * sizeof(bf16));

    size_t avail   = ws_size - off - 256;
    size_t per_row = (size_t)K1 * sizeof(bf16) + (size_t)HID * sizeof(bf16); // 2688 B
    size_t chunk   = (avail / per_row) & ~(size_t)1023;   // multiple of 1024 rows
    if (chunk > (size_t)Bn) chunk = Bn;
    bf16* featc = (bf16*)take(chunk * K1 * sizeof(bf16));
    bf16* X1c   = (bf16*)take(chunk * HID * sizeof(bf16));

    zero_kernel<<<(Bn + 255) / 256, 256, 0, stream>>>(outf, Bn);
    transpose_w1_pad32<<<(HID * K1 + 255) / 256, 256, 0, stream>>>(W1, W1T);
    {
        dim3 g2(HID / 64, HID / 64);
        transpose_pad_tiled<<<g2, 256, 0, stream>>>(W2, W2T, HID, HID, HID);
    }

    for (size_t r0 = 0; r0 < (size_t)Bn; r0 += chunk) {
        size_t rows = ((size_t)Bn - r0 < chunk) ? ((size_t)Bn - r0) : chunk;
        int mt = (int)(rows / 128);
        feat_kernel<<<(unsigned)(rows / 128), 256, 0, stream>>>(S + r0 * 30, E, featc);
        gemm_kernel<0, 320, 320><<<(unsigned)(mt * 8), 256, 0, stream>>>(
            featc, W1T, b1, X1c, nullptr, nullptr, K1, HID, mt);
        gemm_kernel<1, 1024, 1024><<<(unsigned)(mt * 8), 256, 0, stream>>>(
            X1c, W2T, b2, nullptr, outf + r0, W3, HID, 0, mt);
    }
    final_kernel<<<(Bn + 255) / 256, 256, 0, stream>>>(outf, b3, out, Bn);
}

// Round 12
// 576.118 us; speedup vs baseline: 1.5857x; 1.5857x over previous
//
#include <hip/hip_runtime.h>
#include <hip/hip_bf16.h>
#include <stdint.h>
#include <stddef.h>

typedef __hip_bfloat16 bf16;
typedef __attribute__((ext_vector_type(8))) __bf16 bf16x8;
typedef __attribute__((ext_vector_type(16))) float f32x16;

__device__ __forceinline__ bf16 f2b(float x) { return __float2bfloat16(x); }

// async global->LDS copy, 16B per lane. LDS dest must be wave-uniform base + lane*16.
__device__ __forceinline__ void async_copy16(const bf16* g, bf16* l) {
    __builtin_amdgcn_global_load_lds(
        (const __attribute__((address_space(1))) unsigned int*)g,
        (__attribute__((address_space(3))) unsigned int*)l,
        16, 0, 0);
}

// XCD-aware remap: blocks dispatch round-robin to 8 XCDs by l%8. Map each group of
// 64 consecutive l to 8 m-tiles x 8 n-tiles so the 8 blocks of one XCD share ONE
// m-tile -> A row-tile fetched once into that XCD's L2. (r8: FETCH 1.05GB -> 128MB)
__device__ __forceinline__ void remap_xcd(int l, int mt, int& mtile, int& ntile) {
    int g  = l >> 6;
    int r  = l & 63;
    int gm = g << 3;
    if (gm + 8 <= mt) { mtile = gm + (r & 7); ntile = r >> 3; }
    else { int p = mt - gm; mtile = gm + (r % p); ntile = r / p; }  // tail group
}

// ---------------------------------------------------------------- utility kernels
__global__ void zero_kernel(float* __restrict__ p, int n) {
    int i = blockIdx.x * blockDim.x + threadIdx.x;
    if (i < n) p[i] = 0.f;
}

// W1T[n*320 + p]: padded-triplet layout. p = t*32 + q; q<30 -> W1[(t*30+q)*1024 + n], else 0.
__global__ void transpose_w1_pad32(const float* __restrict__ W1, bf16* __restrict__ WT) {
    int idx = blockIdx.x * blockDim.x + threadIdx.x;
    if (idx >= 1024 * 320) return;
    int n = idx / 320;
    int p = idx - n * 320;
    int t = p >> 5;
    int q = p & 31;
    float v = (q < 30) ? W1[(size_t)(t * 30 + q) * 1024 + n] : 0.f;
    WT[idx] = f2b(v);
}

// Tiled transpose+cast for W2: WT[n*Kpad+k] = bf16(W[k*N+n]). 64x64 tiles via LDS.
__global__ __launch_bounds__(256)
void transpose_pad_tiled(const float* __restrict__ W, bf16* __restrict__ WT,
                         int K, int N, int Kpad) {
    __shared__ bf16 tile[64][65];
    const int t = threadIdx.x;
    const int tk = blockIdx.x * 64;
    const int tn = blockIdx.y * 64;
    #pragma unroll
    for (int r = 0; r < 16; ++r) {
        int kl = (t >> 6) + r * 4;
        int nl = t & 63;
        int k = tk + kl, n = tn + nl;
        float v = (k < K) ? W[(size_t)k * N + n] : 0.f;
        tile[kl][nl] = f2b(v);
    }
    __syncthreads();
    #pragma unroll
    for (int r = 0; r < 16; ++r) {
        int nl = (t >> 6) + r * 4;
        int kl = t & 63;
        WT[(size_t)(tn + nl) * Kpad + tk + kl] = tile[kl][nl];
    }
}

// ---------------------------------------------------------------- feature kernel (r8 winner)
// 128 rows/block; features computed once, staged in LDS (XOR-swizzled chunks),
// stored fully coalesced bf16x8. feat layout (linear): row*320 + t*32 + q.
__global__ __launch_bounds__(256)
void feat_kernel(const float* __restrict__ S, const float* __restrict__ E,
                 bf16* __restrict__ feat) {
    __shared__ bf16 sF[128 * 320];
    const int tid = threadIdx.x;
    const size_t r0 = (size_t)blockIdx.x * 128;
    const int row = tid >> 1, tp = tid & 1;

    #pragma unroll
    for (int c = 0; c < 5; ++c) {
        int t = c * 2 + tp;
        const float* sp = S + (r0 + row) * 30 + t * 3;
        float fi = sp[0], fj = sp[1], d = sp[2];
        int ii = (int)fi;
        int jj = (int)fj;
        bf16 f[32];
        #pragma unroll
        for (int q = 0; q < 10; ++q) f[q]      = f2b((ii != 0) ? E[ii * 10 + q] : 0.f);
        #pragma unroll
        for (int q = 0; q < 10; ++q) f[10 + q] = f2b((jj != 0) ? E[jj * 10 + q] : 0.f);
        #pragma unroll
        for (int q = 0; q < 10; ++q) {
            float df = (float)(q + 1) * 0.7f - d;
            f[20 + q] = f2b((ii != 0) ? __expf(-df * df) : 0.f);   // GAMMA = 1
        }
        f[30] = f2b(0.f);
        f[31] = f2b(0.f);
        #pragma unroll
        for (int j = 0; j < 4; ++j) {
            int c0 = t * 4 + j;
            *(bf16x8*)&sF[row * 320 + ((c0 ^ (row & 7)) << 3)] = *(const bf16x8*)&f[j * 8];
        }
    }
    __syncthreads();
    #pragma unroll
    for (int i = 0; i < 20; ++i) {
        int c2 = i * 256 + tid;        // 0..5119
        int r  = c2 / 40;
        int c  = c2 - r * 40;
        int p  = c ^ (r & 7);
        *(bf16x8*)(feat + r0 * 320 + (size_t)c2 * 8) = *(const bf16x8*)&sF[r * 320 + p * 8];
    }
}

// ---------------------------------------------------------------- MFMA GEMM (r10 staging + 32x32x16 core)
// C[M,N] = A[M,K] @ BT[N,K]^T ; 128x128 tile, BK=64, 4 waves (2x2).
// r12: 32x32x16 MFMA (wave-tile 64x64 = 2x2 frags): same FLOP in half the MFMA
// issues (~128 vs ~155 matrix-pipe cyc/K-chunk; ubench 2382-2495 vs 2075 TF).
// A-frag: A[m=lane&31][k=(lane>>5)*8+j]; C/D: col=lane&31,
// row=(reg&3)+8*(reg>>2)+4*(lane>>5) [m74/m101 verified]. Staging, XOR swizzle,
// XCD remap, full K-unroll identical to r10 (do NOT load A per-lane from global:
// r11 showed scatter reads collapse VMEM throughput, 2x regression).
// EPI==0: C = relu(acc + bias) stored bf16.   EPI==1: outf[row] += relu-dot-w3.
template <int EPI, int KTOTAL>
__global__ __launch_bounds__(256)
void gemm_kernel(const bf16* __restrict__ A, const bf16* __restrict__ BT,
                 const float* __restrict__ bias, bf16* __restrict__ C,
                 float* __restrict__ outf, const float* __restrict__ w3,
                 int lda, int ldbt, int ldc, int mt) {
    __shared__ bf16 sA[128 * 64];
    __shared__ bf16 sB[128 * 64];
    const int tid  = threadIdx.x;
    const int lane = tid & 63;
    const int wave = tid >> 6;
    const int wr = wave >> 1, wc = wave & 1;
    const int l32 = lane & 31, half = lane >> 5;
    int mtile, ntile;
    remap_xcd(blockIdx.x, mt, mtile, ntile);
    const size_t m0 = (size_t)mtile * 128;
    const int    n0 = ntile * 128;

    // loop-invariant staging bases (kk becomes an immediate after full unroll)
    const bf16* gA[4];
    const bf16* gB[4];
    #pragma unroll
    for (int i = 0; i < 4; ++i) {
        int s   = i * 256 + tid;
        int row = s >> 3;
        int kof = (((s & 7) ^ (row & 7)) << 3);
        gA[i] = A  + (m0 + row) * lda          + kof;
        gB[i] = BT + (size_t)(n0 + row) * ldbt + kof;
    }

    f32x16 acc[2][2];
    #pragma unroll
    for (int i = 0; i < 2; ++i)
        #pragma unroll
        for (int j = 0; j < 2; ++j)
            #pragma unroll
            for (int e = 0; e < 16; ++e) acc[i][j][e] = 0.f;

    #pragma unroll
    for (int kk = 0; kk < KTOTAL; kk += 64) {
        #pragma unroll
        for (int i = 0; i < 4; ++i) {
            int s = i * 256 + tid;
            async_copy16(gA[i] + kk, &sA[s * 8]);
            async_copy16(gB[i] + kk, &sB[s * 8]);
        }
        __syncthreads();
        #pragma unroll
        for (int st = 0; st < 4; ++st) {             // four k=16 steps per BK=64
            int c = st * 2 + half;                   // logical 16B chunk 0..7
            bf16x8 a[2], b[2];
            #pragma unroll
            for (int mi = 0; mi < 2; ++mi) {
                int r = wr * 64 + mi * 32 + l32;
                a[mi] = *(const bf16x8*)&sA[r * 64 + ((c ^ (r & 7)) << 3)];
            }
            #pragma unroll
            for (int ni = 0; ni < 2; ++ni) {
                int r = wc * 64 + ni * 32 + l32;
                b[ni] = *(const bf16x8*)&sB[r * 64 + ((c ^ (r & 7)) << 3)];
            }
            #pragma unroll
            for (int mi = 0; mi < 2; ++mi)
                #pragma unroll
                for (int ni = 0; ni < 2; ++ni)
                    acc[mi][ni] = __builtin_amdgcn_mfma_f32_32x32x16_bf16(
                        a[mi], b[ni], acc[mi][ni], 0, 0, 0);
        }
        __syncthreads();
    }

    if (EPI == 0) {
        #pragma unroll
        for (int mi = 0; mi < 2; ++mi) {
            #pragma unroll
            for (int ni = 0; ni < 2; ++ni) {
                int col = n0 + wc * 64 + ni * 32 + l32;
                float bv = bias[col];
                #pragma unroll
                for (int reg = 0; reg < 16; ++reg) {
                    int rl = wr * 64 + mi * 32 + (reg & 3) + 8 * (reg >> 2) + 4 * half;
                    float v = acc[mi][ni][reg] + bv;
                    v = v > 0.f ? v : 0.f;
                    C[(m0 + rl) * ldc + col] = f2b(v);
                }
            }
        }
    } else {
        #pragma unroll
        for (int mi = 0; mi < 2; ++mi) {
            float bv[2], wv[2];
            #pragma unroll
            for (int ni = 0; ni < 2; ++ni) {
                int col = n0 + wc * 64 + ni * 32 + l32;
                bv[ni] = bias[col];
                wv[ni] = w3[col];
            }
            #pragma unroll
            for (int reg = 0; reg < 16; ++reg) {
                float p = 0.f;
                #pragma unroll
                for (int ni = 0; ni < 2; ++ni) {
                    float v = acc[mi][ni][reg] + bv[ni];
                    v = v > 0.f ? v : 0.f;
                    p += v * wv[ni];
                }
                // reduce across the 32 lanes (same half) sharing this row
                #pragma unroll
                for (int off = 1; off < 32; off <<= 1)
                    p += __shfl_xor(p, off, 64);
                if (l32 == 0) {
                    size_t row = m0 + wr * 64 + mi * 32 + (reg & 3) + 8 * (reg >> 2) + 4 * half;
                    atomicAdd(&outf[row], p);
                }
            }
        }
    }
}

__global__ void final_kernel(const float* __restrict__ outf, const float* __restrict__ b3,
                             float* __restrict__ out, int n) {
    int i = blockIdx.x * blockDim.x + threadIdx.x;
    if (i < n) out[i] = outf[i] + b3[0];
}

// ---------------------------------------------------------------- zero-workspace fallback
#define FB_ROWS 8
__global__ __launch_bounds__(256)
void fallback_kernel(const float* __restrict__ S, const float* __restrict__ E,
                     const float* __restrict__ W1, const float* __restrict__ b1,
                     const float* __restrict__ W2, const float* __restrict__ b2,
                     const float* __restrict__ W3, const float* __restrict__ b3,
                     float* __restrict__ out) {
    __shared__ float feat[FB_ROWS][304];
    __shared__ float X1[FB_ROWS][1024];
    __shared__ float red[256];
    const int tid = threadIdx.x;
    const size_t r0 = (size_t)blockIdx.x * FB_ROWS;

    if (tid < FB_ROWS * 10) {
        int r = tid / 10, t = tid - r * 10;
        const float* s = S + (r0 + r) * 30 + t * 3;
        float fi = s[0], fj = s[1], d = s[2];
        int ii = (int)fi;
        int jj = (int)fj;
        float* o = &feat[r][t * 30];
        #pragma unroll
        for (int c = 0; c < 10; ++c) o[c]      = (ii != 0) ? E[ii * 10 + c] : 0.f;
        #pragma unroll
        for (int c = 0; c < 10; ++c) o[10 + c] = (jj != 0) ? E[jj * 10 + c] : 0.f;
        #pragma unroll
        for (int c = 0; c < 10; ++c) {
            float df = (float)(c + 1) * 0.7f - d;
            o[20 + c] = (ii != 0) ? __expf(-df * df) : 0.f;
        }
    }
    __syncthreads();

    for (int i = 0; i < FB_ROWS * 1024 / 256; ++i) {
        int idx = i * 256 + tid;
        int r = idx & (FB_ROWS - 1);
        int c = idx >> 3;
        float a = b1[c];
        for (int k = 0; k < 300; ++k)
            a += feat[r][k] * W1[(size_t)k * 1024 + c];
        X1[r][c] = a > 0.f ? a : 0.f;
    }
    __syncthreads();

    {
        int r  = tid & (FB_ROWS - 1);
        int cg = tid >> 3;
        float acc = 0.f;
        for (int cc = 0; cc < 32; ++cc) {
            int c = cg * 32 + cc;
            float a = b2[c];
            for (int k = 0; k < 1024; ++k)
                a += X1[r][k] * W2[(size_t)k * 1024 + c];
            a = a > 0.f ? a : 0.f;
            acc += a * W3[c];
        }
        red[tid] = acc;
    }
    __syncthreads();
    if (tid < FB_ROWS) {
        float s = 0.f;
        for (int g = 0; g < 32; ++g) s += red[g * FB_ROWS + tid];
        out[r0 + tid] = s + b3[0];
    }
}

// ---------------------------------------------------------------- launch
extern "C" void kernel_launch(void* const* d_in, const int* in_sizes, int n_in,
                              void* d_out, int out_size, void* d_ws, size_t ws_size,
                              hipStream_t stream) {
    const float* S  = (const float*)d_in[0];
    const float* E  = (const float*)d_in[1];
    const float* W1 = (const float*)d_in[2];
    const float* b1 = (const float*)d_in[3];
    const float* W2 = (const float*)d_in[4];
    const float* b2 = (const float*)d_in[5];
    const float* W3 = (const float*)d_in[6];
    const float* b3 = (const float*)d_in[7];
    float* out = (float*)d_out;

    const int Bn  = out_size;   // 131072
    const int HID = 1024;
    const int K1  = 320;

    const size_t MIN_WS = 16u * 1024u * 1024u;
    if (ws_size < MIN_WS) {
        fallback_kernel<<<Bn / FB_ROWS, 256, 0, stream>>>(S, E, W1, b1, W2, b2, W3, b3, out);
        return;
    }

    char* ws = (char*)d_ws;
    size_t off = 0;
    auto take = [&](size_t bytes) { char* p = ws + off; off += (bytes + 255) & ~(size_t)255; return p; };
    float* outf = (float*)take((size_t)Bn * sizeof(float));
    bf16*  W1T  = (bf16*) take((size_t)HID * K1 * sizeof(bf16));
    bf16*  W2T  = (bf16*) take((size_t)HID * HID * sizeof(bf16));

    size_t avail   = ws_size - off - 256;
    size_t per_row = (size_t)K1 * sizeof(bf16) + (size_t)HID * sizeof(bf16); // 2688 B
    size_t chunk   = (avail / per_row) & ~(size_t)1023;   // multiple of 1024 rows
    if (chunk > (size_t)Bn) chunk = Bn;
    bf16* featc = (bf16*)take(chunk * K1 * sizeof(bf16));
    bf16* X1c   = (bf16*)take(chunk * HID * sizeof(bf16));

    zero_kernel<<<(Bn + 255) / 256, 256, 0, stream>>>(outf, Bn);
    transpose_w1_pad32<<<(HID * K1 + 255) / 256, 256, 0, stream>>>(W1, W1T);
    {
        dim3 g2(HID / 64, HID / 64);
        transpose_pad_tiled<<<g2, 256, 0, stream>>>(W2, W2T, HID, HID, HID);
    }

    for (size_t r0 = 0; r0 < (size_t)Bn; r0 += chunk) {
        size_t rows = ((size_t)Bn - r0 < chunk) ? ((size_t)Bn - r0) : chunk;
        int mt = (int)(rows / 128);
        feat_kernel<<<(unsigned)(rows / 128), 256, 0, stream>>>(S + r0 * 30, E, featc);
        gemm_kernel<0, 320><<<(unsigned)(mt * 8), 256, 0, stream>>>(
            featc, W1T, b1, X1c, nullptr, nullptr, K1, K1, HID, mt);
        gemm_kernel<1, 1024><<<(unsigned)(mt * 8), 256, 0, stream>>>(
            X1c, W2T, b2, nullptr, outf + r0, W3, HID, HID, 0, mt);
    }
    final_kernel<<<(Bn + 255) / 256, 256, 0, stream>>>(outf, b3, out, Bn);
}

// Round 14
// 546.607 us; speedup vs baseline: 1.6713x; 1.0540x over previous
//
#include <hip/hip_runtime.h>
#include <hip/hip_bf16.h>
#include <stdint.h>
#include <stddef.h>

typedef __hip_bfloat16 bf16;
typedef __attribute__((ext_vector_type(8))) __bf16 bf16x8;
typedef __attribute__((ext_vector_type(4))) float f32x4;

__device__ __forceinline__ bf16 f2b(float x) { return __float2bfloat16(x); }

// async global->LDS copy, 16B per lane. LDS dest must be wave-uniform base + lane*16.
__device__ __forceinline__ void async_copy16(const bf16* g, bf16* l) {
    __builtin_amdgcn_global_load_lds(
        (const __attribute__((address_space(1))) unsigned int*)g,
        (__attribute__((address_space(3))) unsigned int*)l,
        16, 0, 0);
}

// XCD-aware remap: blocks dispatch round-robin to 8 XCDs by l%8. Map each group of
// 64 consecutive l to 8 m-tiles x 8 n-tiles so the 8 blocks of one XCD share ONE
// m-tile -> A row-tile fetched once into that XCD's L2. (r8: FETCH 1.05GB -> 128MB)
__device__ __forceinline__ void remap_xcd(int l, int mt, int& mtile, int& ntile) {
    int g  = l >> 6;
    int r  = l & 63;
    int gm = g << 3;
    if (gm + 8 <= mt) { mtile = gm + (r & 7); ntile = r >> 3; }
    else { int p = mt - gm; mtile = gm + (r % p); ntile = r / p; }  // tail group
}

// ---------------------------------------------------------------- utility kernels
// W1T[n*320 + p]: padded-triplet layout. p = t*32 + q; q<30 -> W1[(t*30+q)*1024 + n], else 0.
__global__ void transpose_w1_pad32(const float* __restrict__ W1, bf16* __restrict__ WT) {
    int idx = blockIdx.x * blockDim.x + threadIdx.x;
    if (idx >= 1024 * 320) return;
    int n = idx / 320;
    int p = idx - n * 320;
    int t = p >> 5;
    int q = p & 31;
    float v = (q < 30) ? W1[(size_t)(t * 30 + q) * 1024 + n] : 0.f;
    WT[idx] = f2b(v);
}

// Tiled transpose+cast for W2: WT[n*Kpad+k] = bf16(W[k*N+n]). 64x64 tiles via LDS.
__global__ __launch_bounds__(256)
void transpose_pad_tiled(const float* __restrict__ W, bf16* __restrict__ WT,
                         int K, int N, int Kpad) {
    __shared__ bf16 tile[64][65];
    const int t = threadIdx.x;
    const int tk = blockIdx.x * 64;
    const int tn = blockIdx.y * 64;
    #pragma unroll
    for (int r = 0; r < 16; ++r) {
        int kl = (t >> 6) + r * 4;
        int nl = t & 63;
        int k = tk + kl, n = tn + nl;
        float v = (k < K) ? W[(size_t)k * N + n] : 0.f;
        tile[kl][nl] = f2b(v);
    }
    __syncthreads();
    #pragma unroll
    for (int r = 0; r < 16; ++r) {
        int nl = (t >> 6) + r * 4;
        int kl = t & 63;
        WT[(size_t)(tn + nl) * Kpad + tk + kl] = tile[kl][nl];
    }
}

// ---------------------------------------------------------------- feature kernel (r8 winner)
// 128 rows/block; features computed once, staged in LDS (XOR-swizzled chunks),
// stored fully coalesced bf16x8. feat layout (linear): row*320 + t*32 + q.
__global__ __launch_bounds__(256)
void feat_kernel(const float* __restrict__ S, const float* __restrict__ E,
                 bf16* __restrict__ feat) {
    __shared__ bf16 sF[128 * 320];
    const int tid = threadIdx.x;
    const size_t r0 = (size_t)blockIdx.x * 128;
    const int row = tid >> 1, tp = tid & 1;

    #pragma unroll
    for (int c = 0; c < 5; ++c) {
        int t = c * 2 + tp;
        const float* sp = S + (r0 + row) * 30 + t * 3;
        float fi = sp[0], fj = sp[1], d = sp[2];
        int ii = (int)fi;
        int jj = (int)fj;
        bf16 f[32];
        #pragma unroll
        for (int q = 0; q < 10; ++q) f[q]      = f2b((ii != 0) ? E[ii * 10 + q] : 0.f);
        #pragma unroll
        for (int q = 0; q < 10; ++q) f[10 + q] = f2b((jj != 0) ? E[jj * 10 + q] : 0.f);
        #pragma unroll
        for (int q = 0; q < 10; ++q) {
            float df = (float)(q + 1) * 0.7f - d;
            f[20 + q] = f2b((ii != 0) ? __expf(-df * df) : 0.f);   // GAMMA = 1
        }
        f[30] = f2b(0.f);
        f[31] = f2b(0.f);
        #pragma unroll
        for (int j = 0; j < 4; ++j) {
            int c0 = t * 4 + j;
            *(bf16x8*)&sF[row * 320 + ((c0 ^ (row & 7)) << 3)] = *(const bf16x8*)&f[j * 8];
        }
    }
    __syncthreads();
    #pragma unroll
    for (int i = 0; i < 20; ++i) {
        int c2 = i * 256 + tid;        // 0..5119
        int r  = c2 / 40;
        int c  = c2 - r * 40;
        int p  = c ^ (r & 7);
        *(bf16x8*)(feat + r0 * 320 + (size_t)c2 * 8) = *(const bf16x8*)&sF[r * 320 + p * 8];
    }
}

// ---------------------------------------------------------------- MFMA GEMM (r10 core)
// C[M,N] = A[M,K] @ BT[N,K]^T ; 128x128 tile, BK=64, 4 waves (2x2), 4x4 16x16x32 frags.
// XOR-swizzled LDS (16B chunk c of row r at c^(r&7)) -- conflict-free ONLY with the
// quad(16-lane)-period fragment reads of the 16x16x32 shape (r12: 32x32 frags broke it).
// Full K-unroll (KTOTAL template) -> addresses immediate-folded (r10: VALUBusy 53->23).
// Staging via global_load_lds only (r11: per-lane global A-frag gathers = 2x loss).
// EPI==0: C = relu(acc + bias) stored bf16.
// EPI==1: outf16[row*16 + ntile*2 + wc] = partial over this wave's 64 cols.
//         (r13 bug: 8-slot indexing let the wc=0/wc=1 waves of the same row
//          overwrite each other -- 16 slots gives every (row,ntile,wc) a unique owner.)
template <int EPI, int KTOTAL>
__global__ __launch_bounds__(256)
void gemm_kernel(const bf16* __restrict__ A, const bf16* __restrict__ BT,
                 const float* __restrict__ bias, bf16* __restrict__ C,
                 float* __restrict__ outf16, const float* __restrict__ w3,
                 int lda, int ldbt, int ldc, int mt) {
    __shared__ bf16 sA[128 * 64];
    __shared__ bf16 sB[128 * 64];
    const int tid  = threadIdx.x;
    const int lane = tid & 63;
    const int wave = tid >> 6;
    const int wr = wave >> 1, wc = wave & 1;
    const int l16 = lane & 15, quad = lane >> 4;
    int mtile, ntile;
    remap_xcd(blockIdx.x, mt, mtile, ntile);
    const size_t m0 = (size_t)mtile * 128;
    const int    n0 = ntile * 128;

    // loop-invariant staging bases (kk becomes an immediate after full unroll)
    const bf16* gA[4];
    const bf16* gB[4];
    #pragma unroll
    for (int i = 0; i < 4; ++i) {
        int s   = i * 256 + tid;
        int row = s >> 3;
        int kof = (((s & 7) ^ (row & 7)) << 3);
        gA[i] = A  + (m0 + row) * lda          + kof;
        gB[i] = BT + (size_t)(n0 + row) * ldbt + kof;
    }

    f32x4 acc[4][4];
    #pragma unroll
    for (int i = 0; i < 4; ++i)
        #pragma unroll
        for (int j = 0; j < 4; ++j) acc[i][j] = (f32x4){0.f, 0.f, 0.f, 0.f};

    #pragma unroll
    for (int kk = 0; kk < KTOTAL; kk += 64) {
        #pragma unroll
        for (int i = 0; i < 4; ++i) {
            int s = i * 256 + tid;
            async_copy16(gA[i] + kk, &sA[s * 8]);
            async_copy16(gB[i] + kk, &sB[s * 8]);
        }
        __syncthreads();
        #pragma unroll
        for (int s2 = 0; s2 < 2; ++s2) {
            int clog = s2 * 4 + quad;
            bf16x8 a[4], b[4];
            #pragma unroll
            for (int mi = 0; mi < 4; ++mi) {
                int r = wr * 64 + mi * 16 + l16;
                a[mi] = *(const bf16x8*)&sA[r * 64 + ((clog ^ (r & 7)) << 3)];
            }
            #pragma unroll
            for (int ni = 0; ni < 4; ++ni) {
                int r = wc * 64 + ni * 16 + l16;
                b[ni] = *(const bf16x8*)&sB[r * 64 + ((clog ^ (r & 7)) << 3)];
            }
            #pragma unroll
            for (int mi = 0; mi < 4; ++mi)
                #pragma unroll
                for (int ni = 0; ni < 4; ++ni)
                    acc[mi][ni] = __builtin_amdgcn_mfma_f32_16x16x32_bf16(
                        a[mi], b[ni], acc[mi][ni], 0, 0, 0);
        }
        __syncthreads();
    }

    if (EPI == 0) {
        #pragma unroll
        for (int mi = 0; mi < 4; ++mi) {
            #pragma unroll
            for (int ni = 0; ni < 4; ++ni) {
                int col = n0 + wc * 64 + ni * 16 + l16;
                float bv = bias[col];
                #pragma unroll
                for (int r = 0; r < 4; ++r) {
                    size_t row = m0 + wr * 64 + mi * 16 + quad * 4 + r;
                    float v = acc[mi][ni][r] + bv;
                    v = v > 0.f ? v : 0.f;
                    C[row * ldc + col] = f2b(v);
                }
            }
        }
    } else {
        // each (row, ntile, wc) triple owned by exactly one wave -> plain store
        #pragma unroll
        for (int mi = 0; mi < 4; ++mi) {
            #pragma unroll
            for (int r = 0; r < 4; ++r) {
                float p = 0.f;
                #pragma unroll
                for (int ni = 0; ni < 4; ++ni) {
                    int col = n0 + wc * 64 + ni * 16 + l16;
                    float v = acc[mi][ni][r] + bias[col];
                    v = v > 0.f ? v : 0.f;
                    p += v * w3[col];
                }
                #pragma unroll
                for (int off = 1; off < 16; off <<= 1)
                    p += __shfl_xor(p, off, 64);
                if (l16 == 0) {
                    size_t row = m0 + wr * 64 + mi * 16 + quad * 4 + r;
                    outf16[row * 16 + ntile * 2 + wc] = p;
                }
            }
        }
    }
}

// out[i] = b3 + sum of 16 per-(n-tile, col-half) partials (64B contiguous read)
__global__ void final_kernel(const float* __restrict__ outf16, const float* __restrict__ b3,
                             float* __restrict__ out, int n) {
    int i = blockIdx.x * blockDim.x + threadIdx.x;
    if (i >= n) return;
    const float* p = outf16 + (size_t)i * 16;
    float s = 0.f;
    #pragma unroll
    for (int j = 0; j < 16; ++j) s += p[j];
    out[i] = s + b3[0];
}

// ---------------------------------------------------------------- zero-workspace fallback
#define FB_ROWS 8
__global__ __launch_bounds__(256)
void fallback_kernel(const float* __restrict__ S, const float* __restrict__ E,
                     const float* __restrict__ W1, const float* __restrict__ b1,
                     const float* __restrict__ W2, const float* __restrict__ b2,
                     const float* __restrict__ W3, const float* __restrict__ b3,
                     float* __restrict__ out) {
    __shared__ float feat[FB_ROWS][304];
    __shared__ float X1[FB_ROWS][1024];
    __shared__ float red[256];
    const int tid = threadIdx.x;
    const size_t r0 = (size_t)blockIdx.x * FB_ROWS;

    if (tid < FB_ROWS * 10) {
        int r = tid / 10, t = tid - r * 10;
        const float* s = S + (r0 + r) * 30 + t * 3;
        float fi = s[0], fj = s[1], d = s[2];
        int ii = (int)fi;
        int jj = (int)fj;
        float* o = &feat[r][t * 30];
        #pragma unroll
        for (int c = 0; c < 10; ++c) o[c]      = (ii != 0) ? E[ii * 10 + c] : 0.f;
        #pragma unroll
        for (int c = 0; c < 10; ++c) o[10 + c] = (jj != 0) ? E[jj * 10 + c] : 0.f;
        #pragma unroll
        for (int c = 0; c < 10; ++c) {
            float df = (float)(c + 1) * 0.7f - d;
            o[20 + c] = (ii != 0) ? __expf(-df * df) : 0.f;
        }
    }
    __syncthreads();

    for (int i = 0; i < FB_ROWS * 1024 / 256; ++i) {
        int idx = i * 256 + tid;
        int r = idx & (FB_ROWS - 1);
        int c = idx >> 3;
        float a = b1[c];
        for (int k = 0; k < 300; ++k)
            a += feat[r][k] * W1[(size_t)k * 1024 + c];
        X1[r][c] = a > 0.f ? a : 0.f;
    }
    __syncthreads();

    {
        int r  = tid & (FB_ROWS - 1);
        int cg = tid >> 3;
        float acc = 0.f;
        for (int cc = 0; cc < 32; ++cc) {
            int c = cg * 32 + cc;
            float a = b2[c];
            for (int k = 0; k < 1024; ++k)
                a += X1[r][k] * W2[(size_t)k * 1024 + c];
            a = a > 0.f ? a : 0.f;
            acc += a * W3[c];
        }
        red[tid] = acc;
    }
    __syncthreads();
    if (tid < FB_ROWS) {
        float s = 0.f;
        for (int g = 0; g < 32; ++g) s += red[g * FB_ROWS + tid];
        out[r0 + tid] = s + b3[0];
    }
}

// ---------------------------------------------------------------- launch
extern "C" void kernel_launch(void* const* d_in, const int* in_sizes, int n_in,
                              void* d_out, int out_size, void* d_ws, size_t ws_size,
                              hipStream_t stream) {
    const float* S  = (const float*)d_in[0];
    const float* E  = (const float*)d_in[1];
    const float* W1 = (const float*)d_in[2];
    const float* b1 = (const float*)d_in[3];
    const float* W2 = (const float*)d_in[4];
    const float* b2 = (const float*)d_in[5];
    const float* W3 = (const float*)d_in[6];
    const float* b3 = (const float*)d_in[7];
    float* out = (float*)d_out;

    const int Bn  = out_size;   // 131072
    const int HID = 1024;
    const int K1  = 320;

    const size_t MIN_WS = 48u * 1024u * 1024u;
    if (ws_size < MIN_WS) {
        fallback_kernel<<<Bn / FB_ROWS, 256, 0, stream>>>(S, E, W1, b1, W2, b2, W3, b3, out);
        return;
    }

    char* ws = (char*)d_ws;
    size_t off = 0;
    auto take = [&](size_t bytes) { char* p = ws + off; off += (bytes + 255) & ~(size_t)255; return p; };
    float* outf16 = (float*)take((size_t)Bn * 16 * sizeof(float));  // per-(ntile,wc) partials
    bf16*  W1T    = (bf16*) take((size_t)HID * K1 * sizeof(bf16));
    bf16*  W2T    = (bf16*) take((size_t)HID * HID * sizeof(bf16));

    size_t avail   = ws_size - off - 256;
    size_t per_row = (size_t)K1 * sizeof(bf16) + (size_t)HID * sizeof(bf16); // 2688 B
    size_t chunk   = (avail / per_row) & ~(size_t)1023;   // multiple of 1024 rows
    if (chunk > (size_t)Bn) chunk = Bn;
    bf16* featc = (bf16*)take(chunk * K1 * sizeof(bf16));
    bf16* X1c   = (bf16*)take(chunk * HID * sizeof(bf16));

    transpose_w1_pad32<<<(HID * K1 + 255) / 256, 256, 0, stream>>>(W1, W1T);
    {
        dim3 g2(HID / 64, HID / 64);
        transpose_pad_tiled<<<g2, 256, 0, stream>>>(W2, W2T, HID, HID, HID);
    }

    for (size_t r0 = 0; r0 < (size_t)Bn; r0 += chunk) {
        size_t rows = ((size_t)Bn - r0 < chunk) ? ((size_t)Bn - r0) : chunk;
        int mt = (int)(rows / 128);
        feat_kernel<<<(unsigned)(rows / 128), 256, 0, stream>>>(S + r0 * 30, E, featc);
        gemm_kernel<0, 320><<<(unsigned)(mt * 8), 256, 0, stream>>>(
            featc, W1T, b1, X1c, nullptr, nullptr, K1, K1, HID, mt);
        gemm_kernel<1, 1024><<<(unsigned)(mt * 8), 256, 0, stream>>>(
            X1c, W2T, b2, nullptr, outf16 + r0 * 16, W3, HID, HID, 0, mt);
    }
    final_kernel<<<(Bn + 255) / 256, 256, 0, stream>>>(outf16, b3, out, Bn);
}

// Round 15
// 537.654 us; speedup vs baseline: 1.6991x; 1.0167x over previous
//
#include <hip/hip_runtime.h>
#include <hip/hip_bf16.h>
#include <stdint.h>
#include <stddef.h>

typedef __hip_bfloat16 bf16;
typedef __attribute__((ext_vector_type(8))) __bf16 bf16x8;
typedef __attribute__((ext_vector_type(4))) float f32x4;

__device__ __forceinline__ bf16 f2b(float x) { return __float2bfloat16(x); }

// async global->LDS copy, 16B per lane. LDS dest must be wave-uniform base + lane*16.
__device__ __forceinline__ void async_copy16(const bf16* g, bf16* l) {
    __builtin_amdgcn_global_load_lds(
        (const __attribute__((address_space(1))) unsigned int*)g,
        (__attribute__((address_space(3))) unsigned int*)l,
        16, 0, 0);
}

// XCD-aware remap: blocks dispatch round-robin to 8 XCDs by l%8. Map each group of
// 64 consecutive l to 8 m-tiles x 8 n-tiles so the 8 blocks of one XCD share ONE
// m-tile -> A row-tile fetched once into that XCD's L2. (r8: FETCH 1.05GB -> 128MB)
__device__ __forceinline__ void remap_xcd(int l, int mt, int& mtile, int& ntile) {
    int g  = l >> 6;
    int r  = l & 63;
    int gm = g << 3;
    if (gm + 8 <= mt) { mtile = gm + (r & 7); ntile = r >> 3; }
    else { int p = mt - gm; mtile = gm + (r % p); ntile = r / p; }  // tail group
}

// ---------------------------------------------------------------- merged weight transpose
// blocks [0,256): W2 64x64 tiles via LDS -> W2T[n*1024+k].
// blocks [256,1536): element-wise W1 -> W1T[n*320 + t*32 + q] (padded-triplet layout).
__global__ __launch_bounds__(256)
void transpose_weights(const float* __restrict__ W1, bf16* __restrict__ W1T,
                       const float* __restrict__ W2, bf16* __restrict__ W2T) {
    __shared__ bf16 tile[64][65];
    const int bx = blockIdx.x;
    const int t  = threadIdx.x;
    if (bx < 256) {
        const int tk = (bx & 15) * 64;
        const int tn = (bx >> 4) * 64;
        #pragma unroll
        for (int r = 0; r < 16; ++r) {
            int kl = (t >> 6) + r * 4;
            int nl = t & 63;
            tile[kl][nl] = f2b(W2[(size_t)(tk + kl) * 1024 + tn + nl]);
        }
        __syncthreads();
        #pragma unroll
        for (int r = 0; r < 16; ++r) {
            int nl = (t >> 6) + r * 4;
            int kl = t & 63;
            W2T[(size_t)(tn + nl) * 1024 + tk + kl] = tile[kl][nl];
        }
    } else {
        int idx = (bx - 256) * 256 + t;          // 0 .. 1024*320-1
        if (idx < 1024 * 320) {
            int n = idx / 320;
            int p = idx - n * 320;
            int tt = p >> 5;
            int q  = p & 31;
            float v = (q < 30) ? W1[(size_t)(tt * 30 + q) * 1024 + n] : 0.f;
            W1T[idx] = f2b(v);
        }
    }
}

// ---------------------------------------------------------------- feature kernel (r8 winner)
// 128 rows/block; features computed once, staged in LDS (XOR-swizzled chunks),
// stored fully coalesced bf16x8. feat layout (linear): row*320 + t*32 + q.
__global__ __launch_bounds__(256)
void feat_kernel(const float* __restrict__ S, const float* __restrict__ E,
                 bf16* __restrict__ feat) {
    __shared__ bf16 sF[128 * 320];
    const int tid = threadIdx.x;
    const size_t r0 = (size_t)blockIdx.x * 128;
    const int row = tid >> 1, tp = tid & 1;

    #pragma unroll
    for (int c = 0; c < 5; ++c) {
        int t = c * 2 + tp;
        const float* sp = S + (r0 + row) * 30 + t * 3;
        float fi = sp[0], fj = sp[1], d = sp[2];
        int ii = (int)fi;
        int jj = (int)fj;
        bf16 f[32];
        #pragma unroll
        for (int q = 0; q < 10; ++q) f[q]      = f2b((ii != 0) ? E[ii * 10 + q] : 0.f);
        #pragma unroll
        for (int q = 0; q < 10; ++q) f[10 + q] = f2b((jj != 0) ? E[jj * 10 + q] : 0.f);
        #pragma unroll
        for (int q = 0; q < 10; ++q) {
            float df = (float)(q + 1) * 0.7f - d;
            f[20 + q] = f2b((ii != 0) ? __expf(-df * df) : 0.f);   // GAMMA = 1
        }
        f[30] = f2b(0.f);
        f[31] = f2b(0.f);
        #pragma unroll
        for (int j = 0; j < 4; ++j) {
            int c0 = t * 4 + j;
            *(bf16x8*)&sF[row * 320 + ((c0 ^ (row & 7)) << 3)] = *(const bf16x8*)&f[j * 8];
        }
    }
    __syncthreads();
    #pragma unroll
    for (int i = 0; i < 20; ++i) {
        int c2 = i * 256 + tid;        // 0..5119
        int r  = c2 / 40;
        int c  = c2 - r * 40;
        int p  = c ^ (r & 7);
        *(bf16x8*)(feat + r0 * 320 + (size_t)c2 * 8) = *(const bf16x8*)&sF[r * 320 + p * 8];
    }
}

// ---------------------------------------------------------------- MFMA GEMM (r10 core)
// C[M,N] = A[M,K] @ BT[N,K]^T ; 128x128 tile, BK=64, 4 waves (2x2), 4x4 16x16x32 frags.
// XOR-swizzled LDS (16B chunk c of row r at c^(r&7)) -- conflict-free ONLY with the
// quad(16-lane)-period fragment reads of the 16x16x32 shape (r12: 32x32 frags broke it).
// Full K-unroll (KTOTAL template) -> addresses immediate-folded (r10: VALUBusy 53->23).
// Staging via global_load_lds only (r11: per-lane global A-frag gathers = 2x loss).
// EPI==0: C = relu(acc + bias) stored bf16.
// EPI==1: per-row partials over this wave's 64 cols; wc=0/wc=1 combined via LDS
//         (r13 bug: both wc waves of a row must contribute), single plain store to
//         outf8[row*8 + ntile]. No atomics, no zero pass.
template <int EPI, int KTOTAL>
__global__ __launch_bounds__(256)
void gemm_kernel(const bf16* __restrict__ A, const bf16* __restrict__ BT,
                 const float* __restrict__ bias, bf16* __restrict__ C,
                 float* __restrict__ outf8, const float* __restrict__ w3,
                 int lda, int ldbt, int ldc, int mt) {
    __shared__ bf16 sA[128 * 64];
    __shared__ bf16 sB[128 * 64];
    __shared__ float sRed[128];
    const int tid  = threadIdx.x;
    const int lane = tid & 63;
    const int wave = tid >> 6;
    const int wr = wave >> 1, wc = wave & 1;
    const int l16 = lane & 15, quad = lane >> 4;
    int mtile, ntile;
    remap_xcd(blockIdx.x, mt, mtile, ntile);
    const size_t m0 = (size_t)mtile * 128;
    const int    n0 = ntile * 128;

    // loop-invariant staging bases (kk becomes an immediate after full unroll)
    const bf16* gA[4];
    const bf16* gB[4];
    #pragma unroll
    for (int i = 0; i < 4; ++i) {
        int s   = i * 256 + tid;
        int row = s >> 3;
        int kof = (((s & 7) ^ (row & 7)) << 3);
        gA[i] = A  + (m0 + row) * lda          + kof;
        gB[i] = BT + (size_t)(n0 + row) * ldbt + kof;
    }

    f32x4 acc[4][4];
    #pragma unroll
    for (int i = 0; i < 4; ++i)
        #pragma unroll
        for (int j = 0; j < 4; ++j) acc[i][j] = (f32x4){0.f, 0.f, 0.f, 0.f};

    #pragma unroll
    for (int kk = 0; kk < KTOTAL; kk += 64) {
        #pragma unroll
        for (int i = 0; i < 4; ++i) {
            int s = i * 256 + tid;
            async_copy16(gA[i] + kk, &sA[s * 8]);
            async_copy16(gB[i] + kk, &sB[s * 8]);
        }
        __syncthreads();
        #pragma unroll
        for (int s2 = 0; s2 < 2; ++s2) {
            int clog = s2 * 4 + quad;
            bf16x8 a[4], b[4];
            #pragma unroll
            for (int mi = 0; mi < 4; ++mi) {
                int r = wr * 64 + mi * 16 + l16;
                a[mi] = *(const bf16x8*)&sA[r * 64 + ((clog ^ (r & 7)) << 3)];
            }
            #pragma unroll
            for (int ni = 0; ni < 4; ++ni) {
                int r = wc * 64 + ni * 16 + l16;
                b[ni] = *(const bf16x8*)&sB[r * 64 + ((clog ^ (r & 7)) << 3)];
            }
            #pragma unroll
            for (int mi = 0; mi < 4; ++mi)
                #pragma unroll
                for (int ni = 0; ni < 4; ++ni)
                    acc[mi][ni] = __builtin_amdgcn_mfma_f32_16x16x32_bf16(
                        a[mi], b[ni], acc[mi][ni], 0, 0, 0);
        }
        __syncthreads();
    }

    if (EPI == 0) {
        #pragma unroll
        for (int mi = 0; mi < 4; ++mi) {
            #pragma unroll
            for (int ni = 0; ni < 4; ++ni) {
                int col = n0 + wc * 64 + ni * 16 + l16;
                float bv = bias[col];
                #pragma unroll
                for (int r = 0; r < 4; ++r) {
                    size_t row = m0 + wr * 64 + mi * 16 + quad * 4 + r;
                    float v = acc[mi][ni][r] + bv;
                    v = v > 0.f ? v : 0.f;
                    C[row * ldc + col] = f2b(v);
                }
            }
        }
    } else {
        float pArr[4][4];
        #pragma unroll
        for (int mi = 0; mi < 4; ++mi) {
            #pragma unroll
            for (int r = 0; r < 4; ++r) {
                float p = 0.f;
                #pragma unroll
                for (int ni = 0; ni < 4; ++ni) {
                    int col = n0 + wc * 64 + ni * 16 + l16;
                    float v = acc[mi][ni][r] + bias[col];
                    v = v > 0.f ? v : 0.f;
                    p += v * w3[col];
                }
                #pragma unroll
                for (int off = 1; off < 16; off <<= 1)
                    p += __shfl_xor(p, off, 64);
                pArr[mi][r] = p;
            }
        }
        // combine the two col-half waves (wc=0 + wc=1) through LDS, one store per row
        if (wc == 0 && l16 == 0) {
            #pragma unroll
            for (int mi = 0; mi < 4; ++mi)
                #pragma unroll
                for (int r = 0; r < 4; ++r)
                    sRed[wr * 64 + mi * 16 + quad * 4 + r] = pArr[mi][r];
        }
        __syncthreads();
        if (wc == 1 && l16 == 0) {
            #pragma unroll
            for (int mi = 0; mi < 4; ++mi)
                #pragma unroll
                for (int r = 0; r < 4; ++r) {
                    int rl = wr * 64 + mi * 16 + quad * 4 + r;
                    outf8[(m0 + rl) * 8 + ntile] = pArr[mi][r] + sRed[rl];
                }
        }
    }
}

// out[i] = b3 + sum of 8 per-n-tile partials (32B contiguous read per thread)
__global__ void final_kernel(const float* __restrict__ outf8, const float* __restrict__ b3,
                             float* __restrict__ out, int n) {
    int i = blockIdx.x * blockDim.x + threadIdx.x;
    if (i >= n) return;
    const float* p = outf8 + (size_t)i * 8;
    float s = 0.f;
    #pragma unroll
    for (int j = 0; j < 8; ++j) s += p[j];
    out[i] = s + b3[0];
}

// ---------------------------------------------------------------- zero-workspace fallback
#define FB_ROWS 8
__global__ __launch_bounds__(256)
void fallback_kernel(const float* __restrict__ S, const float* __restrict__ E,
                     const float* __restrict__ W1, const float* __restrict__ b1,
                     const float* __restrict__ W2, const float* __restrict__ b2,
                     const float* __restrict__ W3, const float* __restrict__ b3,
                     float* __restrict__ out) {
    __shared__ float feat[FB_ROWS][304];
    __shared__ float X1[FB_ROWS][1024];
    __shared__ float red[256];
    const int tid = threadIdx.x;
    const size_t r0 = (size_t)blockIdx.x * FB_ROWS;

    if (tid < FB_ROWS * 10) {
        int r = tid / 10, t = tid - r * 10;
        const float* s = S + (r0 + r) * 30 + t * 3;
        float fi = s[0], fj = s[1], d = s[2];
        int ii = (int)fi;
        int jj = (int)fj;
        float* o = &feat[r][t * 30];
        #pragma unroll
        for (int c = 0; c < 10; ++c) o[c]      = (ii != 0) ? E[ii * 10 + c] : 0.f;
        #pragma unroll
        for (int c = 0; c < 10; ++c) o[10 + c] = (jj != 0) ? E[jj * 10 + c] : 0.f;
        #pragma unroll
        for (int c = 0; c < 10; ++c) {
            float df = (float)(c + 1) * 0.7f - d;
            o[20 + c] = (ii != 0) ? __expf(-df * df) : 0.f;
        }
    }
    __syncthreads();

    for (int i = 0; i < FB_ROWS * 1024 / 256; ++i) {
        int idx = i * 256 + tid;
        int r = idx & (FB_ROWS - 1);
        int c = idx >> 3;
        float a = b1[c];
        for (int k = 0; k < 300; ++k)
            a += feat[r][k] * W1[(size_t)k * 1024 + c];
        X1[r][c] = a > 0.f ? a : 0.f;
    }
    __syncthreads();

    {
        int r  = tid & (FB_ROWS - 1);
        int cg = tid >> 3;
        float acc = 0.f;
        for (int cc = 0; cc < 32; ++cc) {
            int c = cg * 32 + cc;
            float a = b2[c];
            for (int k = 0; k < 1024; ++k)
                a += X1[r][k] * W2[(size_t)k * 1024 + c];
            a = a > 0.f ? a : 0.f;
            acc += a * W3[c];
        }
        red[tid] = acc;
    }
    __syncthreads();
    if (tid < FB_ROWS) {
        float s = 0.f;
        for (int g = 0; g < 32; ++g) s += red[g * FB_ROWS + tid];
        out[r0 + tid] = s + b3[0];
    }
}

// ---------------------------------------------------------------- launch
extern "C" void kernel_launch(void* const* d_in, const int* in_sizes, int n_in,
                              void* d_out, int out_size, void* d_ws, size_t ws_size,
                              hipStream_t stream) {
    const float* S  = (const float*)d_in[0];
    const float* E  = (const float*)d_in[1];
    const float* W1 = (const float*)d_in[2];
    const float* b1 = (const float*)d_in[3];
    const float* W2 = (const float*)d_in[4];
    const float* b2 = (const float*)d_in[5];
    const float* W3 = (const float*)d_in[6];
    const float* b3 = (const float*)d_in[7];
    float* out = (float*)d_out;

    const int Bn  = out_size;   // 131072
    const int HID = 1024;
    const int K1  = 320;

    const size_t MIN_WS = 48u * 1024u * 1024u;
    if (ws_size < MIN_WS) {
        fallback_kernel<<<Bn / FB_ROWS, 256, 0, stream>>>(S, E, W1, b1, W2, b2, W3, b3, out);
        return;
    }

    char* ws = (char*)d_ws;
    size_t off = 0;
    auto take = [&](size_t bytes) { char* p = ws + off; off += (bytes + 255) & ~(size_t)255; return p; };
    float* outf8 = (float*)take((size_t)Bn * 8 * sizeof(float));   // per-n-tile partials, 4 MB
    bf16*  W1T   = (bf16*) take((size_t)HID * K1 * sizeof(bf16));
    bf16*  W2T   = (bf16*) take((size_t)HID * HID * sizeof(bf16));

    size_t avail   = ws_size - off - 256;
    size_t per_row = (size_t)K1 * sizeof(bf16) + (size_t)HID * sizeof(bf16); // 2688 B
    size_t chunk   = (avail / per_row) & ~(size_t)1023;   // multiple of 1024 rows
    if (chunk > (size_t)Bn) chunk = Bn;
    bf16* featc = (bf16*)take(chunk * K1 * sizeof(bf16));
    bf16* X1c   = (bf16*)take(chunk * HID * sizeof(bf16));

    transpose_weights<<<1536, 256, 0, stream>>>(W1, W1T, W2, W2T);

    for (size_t r0 = 0; r0 < (size_t)Bn; r0 += chunk) {
        size_t rows = ((size_t)Bn - r0 < chunk) ? ((size_t)Bn - r0) : chunk;
        int mt = (int)(rows / 128);
        feat_kernel<<<(unsigned)(rows / 128), 256, 0, stream>>>(S + r0 * 30, E, featc);
        gemm_kernel<0, 320><<<(unsigned)(mt * 8), 256, 0, stream>>>(
            featc, W1T, b1, X1c, nullptr, nullptr, K1, K1, HID, mt);
        gemm_kernel<1, 1024><<<(unsigned)(mt * 8), 256, 0, stream>>>(
            X1c, W2T, b2, nullptr, outf8 + r0 * 8, W3, HID, HID, 0, mt);
    }
    final_kernel<<<(Bn + 255) / 256, 256, 0, stream>>>(outf8, b3, out, Bn);
}